// Round 10
// baseline (2407.057 us; speedup 1.0000x reference)
//
#include <hip/hip_runtime.h>
#include <stdint.h>
#include <stdio.h>

typedef __attribute__((ext_vector_type(8))) short short8;
typedef __attribute__((ext_vector_type(4))) float f32x4;
typedef __attribute__((ext_vector_type(4))) unsigned int u32x4;

#define DEV static __device__ __forceinline__

DEV unsigned short f2bf(float f){
  unsigned u = __float_as_uint(f);
  u += 0x7FFFu + ((u >> 16) & 1u);          // RNE
  return (unsigned short)(u >> 16);
}
DEV float bf2f(unsigned short h){ return __uint_as_float(((unsigned)h) << 16); }

// ---------------------------------------------------------------------------
// x (8,96,256,256) f32  ->  xt (8,260,260,128) bf16 channels-last with halo=2
// ---------------------------------------------------------------------------
__global__ __launch_bounds__(256) void k_xt(const float* __restrict__ x,
                                            unsigned short* __restrict__ xt){
  int bid = blockIdx.x;                 // 8*256*4
  int wq = bid & 3, h = (bid >> 2) & 255, b = bid >> 10;
  int w0 = wq * 64;
  __shared__ unsigned short s[64 * 104];
  int t = threadIdx.x;
  int wl = t & 63, cq = t >> 6;         // cq 0..3
  const float* xp = x + ((size_t)b * 96 * 256 + h) * 256 + w0 + wl;
  #pragma unroll
  for (int i = 0; i < 24; ++i){
    int c = cq + i * 4;                 // 0..95
    s[wl * 104 + c] = f2bf(xp[(size_t)c * 65536]);
  }
  __syncthreads();
  unsigned short* dst = xt + (((size_t)b * 260 + h + 2) * 260 + (w0 + 2)) * 128;
  #pragma unroll
  for (int p = 0; p < 3; ++p){
    int i = t + p * 256;                // 0..767 = 64 w * 12 chunks
    int w = i / 12, ch = i % 12;
    u32x4 v = *(const u32x4*)&s[w * 104 + ch * 8];
    *(u32x4*)&dst[(size_t)w * 128 + ch * 8] = v;
  }
}

// ---------------------------------------------------------------------------
// weight repack (bf16):
//  A2  [768][ (kh*5+kw)*96 + ic ]   patch-conv weights (r then c)
//  Aun [m=co*4+p*2+q][ci 0..767]    unpatch weights
//  Agr [side][m 0..191][k 0..95]    gru weights transposed
//  bun [96] f32 = r_un_b + c_un_b
// ---------------------------------------------------------------------------
__global__ __launch_bounds__(256) void k_pack(const float* __restrict__ rpw, const float* __restrict__ cpw,
    const float* __restrict__ runw, const float* __restrict__ cunw,
    const float* __restrict__ runb, const float* __restrict__ cunb,
    const float* __restrict__ rgw,  const float* __restrict__ cgw,
    unsigned short* __restrict__ A2, unsigned short* __restrict__ Aun,
    unsigned short* __restrict__ Agr, float* __restrict__ bun){
  int tid = blockIdx.x * 256 + threadIdx.x;
  const int NA2 = 768 * 2400, NUN = 384 * 768, NGR = 2 * 192 * 96;
  if (tid < NA2){
    int oc = tid / 2400, r = tid % 2400;
    int kh = r / 480, kw = (r / 96) % 5, ic = r % 96;
    const float* W = oc < 384 ? rpw : cpw;
    int o = oc < 384 ? oc : oc - 384;
    A2[tid] = f2bf(W[(((size_t)o * 96 + ic) * 5 + kh) * 5 + kw]);
  } else if (tid < NA2 + NUN){
    int i = tid - NA2;
    int m = i / 768, ci = i % 768;
    int co = m >> 2, p = (m >> 1) & 1, q = m & 1;
    const float* W = ci < 384 ? runw : cunw;
    int c = ci < 384 ? ci : ci - 384;
    Aun[i] = f2bf(W[(((size_t)c * 96 + co) * 2 + p) * 2 + q]);
  } else if (tid < NA2 + NUN + NGR){
    int i = tid - NA2 - NUN;
    int side = i / 18432, r = i % 18432;
    int m = r / 96, k = r % 96;
    const float* W = side ? cgw : rgw;       // (96,192) row-major
    Agr[i] = f2bf(W[k * 192 + m]);
  } else if (tid < NA2 + NUN + NGR + 96){
    int co = tid - NA2 - NUN - NGR;
    bun[co] = runb[co] + cunb[co];
  }
}

// ---------------------------------------------------------------------------
// patch conv as implicit GEMM, v6b (v6 with the 131-column fix).
// ONE 512-thread block = 8 waves (2 mw x 4 nw), block tile 128oc x 256px
// (4 ho x 64 wo), wave tile 64oc x 64px -> 24 ds_read_b128 per 48 MFMA.
// B per kh in LDS: [4 rows][131 cols][16 ch x 16B] = 134144, XOR swizzle
//   phys = ch ^ ((col>>1)&7).  (cols needed: 2*63+4 = 130 -> 131 columns!)
// A single-buffered [128][208B] = 26624, async reg-prefetch (write after
// barrier).  Next-kh B reg-prefetched under kw==4 compute.  2 barriers/slab.
// LDS total = 160768 -> 1 block/CU = 8 waves/CU.
// ---------------------------------------------------------------------------
__global__ __launch_bounds__(512) void k_conv(const unsigned short* __restrict__ xt,
    const unsigned short* __restrict__ A2,
    const float* __restrict__ rpb, const float* __restrict__ cpb,
    unsigned short* __restrict__ cl){
  __shared__ char lds[160768];
  const int BOFF = 26624;               // B region offset
  const int BPITCH = 33536;             // 131 cols * 256 B
  const int BITEMS = 8384;              // 4 rows * 131 cols * 16 ch
  int t = threadIdx.x, lane = t & 63;
  int wid = t >> 6, mw = wid >> 2, nw = wid & 3;
  int wl = lane & 15, cg = lane >> 4;
  int nt = blockIdx.x;                  // 512 = b(8) * hq(32) * wq(2)
  int wq = nt & 1, hq = (nt >> 1) & 31, b = nt >> 6;
  int ho0 = hq * 4, wo0 = wq * 64;
  int M0 = blockIdx.y * 128;

  // A staging role: oc = t>>2 (0..127), quarter = t&3 (24 elems each)
  int a_oc = t >> 2, a_q = t & 3;
  const unsigned short* Aoc = A2 + (size_t)(M0 + a_oc) * 2400 + a_q * 24;
  char* Adst = lds + a_oc * 208 + a_q * 48;

  f32x4 acc[4][4];
  #pragma unroll
  for (int i = 0; i < 4; ++i)
    #pragma unroll
    for (int j = 0; j < 4; ++j) acc[i][j] = (f32x4){0.f, 0.f, 0.f, 0.f};

  u32x4 aR[3], bR[17];
  // ---- prologue: A(0,0) + B(kh=0) ----
  #pragma unroll
  for (int c = 0; c < 3; ++c) aR[c] = *(const u32x4*)(Aoc + c * 8);
  #pragma unroll
  for (int it = 0; it < 17; ++it){
    int i = t + it * 512;
    if (i < BITEMS){
      int row = i / 2096, j = i % 2096, col = j >> 4, ch = j & 15;
      bR[it] = *(const u32x4*)&xt[(((size_t)b * 260 + 2 * ho0 + 2 * row) * 260 + 2 * wo0 + col) * 128 + ch * 8];
    }
  }
  #pragma unroll
  for (int c = 0; c < 3; ++c) *(u32x4*)(Adst + c * 16) = aR[c];
  #pragma unroll
  for (int it = 0; it < 17; ++it){
    int i = t + it * 512;
    if (i < BITEMS){
      int row = i / 2096, j = i % 2096, col = j >> 4, ch = j & 15;
      *(u32x4*)(lds + BOFF + row * BPITCH + col * 256 + (ch ^ ((col >> 1) & 7)) * 16) = bR[it];
    }
  }
  __syncthreads();

  for (int kh = 0; kh < 5; ++kh){
    #pragma unroll
    for (int kw = 0; kw < 5; ++kw){
      bool last = (kh == 4 && kw == 4);
      bool khb  = (kw == 4 && kh < 4);
      // issue next-slab A prefetch (global -> regs)
      if (!last){
        int nkh = kh + (kw == 4 ? 1 : 0), nkw = (kw == 4 ? 0 : kw + 1);
        const unsigned short* As = Aoc + (nkh * 5 + nkw) * 96;
        #pragma unroll
        for (int c = 0; c < 3; ++c) aR[c] = *(const u32x4*)(As + c * 8);
      }
      // issue next-kh B prefetch (global -> regs), hidden under 48 MFMA
      if (khb){
        #pragma unroll
        for (int it = 0; it < 17; ++it){
          int i = t + it * 512;
          if (i < BITEMS){
            int row = i / 2096, j = i % 2096, col = j >> 4, ch = j & 15;
            bR[it] = *(const u32x4*)&xt[(((size_t)b * 260 + 2 * ho0 + 2 * row + kh + 1) * 260 + 2 * wo0 + col) * 128 + ch * 8];
          }
        }
      }
      // ---- compute slab (kh,kw): 48 MFMA per wave ----
      {
        int col = 32 * nw + 2 * wl + kw;
        int sx = (col >> 1) & 7;
        #pragma unroll
        for (int ics = 0; ics < 3; ++ics){
          short8 af[4], bfr[4];
          #pragma unroll
          for (int mf = 0; mf < 4; ++mf)
            af[mf] = *(const short8*)(lds + (mw * 64 + mf * 16 + wl) * 208 + ics * 64 + cg * 16);
          int chl = (ics * 4 + cg) ^ sx;
          #pragma unroll
          for (int nf = 0; nf < 4; ++nf)
            bfr[nf] = *(const short8*)(lds + BOFF + nf * BPITCH + col * 256 + chl * 16);
          #pragma unroll
          for (int mf = 0; mf < 4; ++mf)
            #pragma unroll
            for (int nf = 0; nf < 4; ++nf)
              acc[mf][nf] = __builtin_amdgcn_mfma_f32_16x16x32_bf16(af[mf], bfr[nf], acc[mf][nf], 0, 0, 0);
        }
      }
      __syncthreads();                  // all waves done reading A/B
      if (!last){
        #pragma unroll
        for (int c = 0; c < 3; ++c) *(u32x4*)(Adst + c * 16) = aR[c];
        if (khb){
          #pragma unroll
          for (int it = 0; it < 17; ++it){
            int i = t + it * 512;
            if (i < BITEMS){
              int row = i / 2096, j = i % 2096, col = j >> 4, ch = j & 15;
              *(u32x4*)(lds + BOFF + row * BPITCH + col * 256 + (ch ^ ((col >> 1) & 7)) * 16) = bR[it];
            }
          }
        }
      }
      __syncthreads();                  // staged data visible
    }
  }
  // epilogue: bias, stash to LDS [256 px][128 oc], cooperative cl write
  unsigned short* S = (unsigned short*)lds;
  #pragma unroll
  for (int mf = 0; mf < 4; ++mf)
    #pragma unroll
    for (int nf = 0; nf < 4; ++nf){
      int wol = nw * 16 + wl;
      #pragma unroll
      for (int j = 0; j < 4; ++j){
        int oc = M0 + mw * 64 + mf * 16 + cg * 4 + j;
        float v = acc[mf][nf][j] + (oc < 384 ? rpb[oc] : cpb[oc - 384]);
        S[(nf * 64 + wol) * 128 + (oc - M0)] = f2bf(v);
      }
    }
  __syncthreads();
  #pragma unroll
  for (int it = 0; it < 8; ++it){
    int i = t + it * 512;               // 0..4095 = 256 px * 16 chunks
    int pxl = i >> 4, ch = i & 15;
    int ho = ho0 + (pxl >> 6), wo = wo0 + (pxl & 63);
    u32x4 v = *(const u32x4*)&S[pxl * 128 + ch * 8];
    *(u32x4*)&cl[(((size_t)b * 128 + ho) * 128 + wo) * 768 + M0 + ch * 8] = v;
  }
}

// ---------------------------------------------------------------------------
// positional grouped conv 3x3 (groups of 4ch), reading channels-last cl.
// ---------------------------------------------------------------------------
__global__ __launch_bounds__(256) void k_pe(const unsigned short* __restrict__ cl,
    const float* __restrict__ rpew, const float* __restrict__ cpew,
    const float* __restrict__ rpeb, const float* __restrict__ cpeb,
    unsigned short* __restrict__ sum){
  __shared__ unsigned short si[48 * 340];  // [48 ch][10 r][34 c]
  __shared__ float sw[48 * 36];
  __shared__ float sb[48];
  int bid = blockIdx.x;                    // 8*16*16*4
  int wq = bid & 3, hq = (bid >> 2) & 15, slab = (bid >> 6) & 15, b = bid >> 10;
  int ch0 = slab * 48, hp0 = hq * 8, wp0 = wq * 32;
  int t = threadIdx.x;
  for (int i = t; i < 48 * 36; i += 256){
    int ocl = i / 36, r = i % 36;
    int oc = ch0 + ocl;
    const float* W = oc < 384 ? rpew : cpew;
    int o = oc < 384 ? oc : oc - 384;
    sw[i] = W[(size_t)o * 36 + r];
  }
  if (t < 48){
    int oc = ch0 + t;
    sb[t] = oc < 384 ? rpeb[oc] : cpeb[oc - 384];
  }
  for (int i = t; i < 340 * 48; i += 256){   // pixel-major: 48ch contiguous
    int pix = i / 48, c = i % 48;
    int r2 = pix / 34, cc = pix % 34;
    int hp = hp0 - 1 + r2, wp = wp0 - 1 + cc;
    unsigned short v = 0;
    if (hp >= 0 && hp < 128 && wp >= 0 && wp < 128)
      v = cl[((size_t)b * 16384 + hp * 128 + wp) * 768 + ch0 + c];
    si[c * 340 + pix] = v;
  }
  __syncthreads();
  int hpl = t >> 5, wpl = t & 31;
  unsigned int outp[24];
  #pragma unroll
  for (int g = 0; g < 12; ++g){
    float win[36];
    #pragma unroll
    for (int ii = 0; ii < 4; ++ii)
      #pragma unroll
      for (int dh = 0; dh < 3; ++dh)
        #pragma unroll
        for (int dw = 0; dw < 3; ++dw)
          win[ii * 9 + dh * 3 + dw] = bf2f(si[(g * 4 + ii) * 340 + (hpl + dh) * 34 + (wpl + dw)]);
    float o[4];
    #pragma unroll
    for (int ol = 0; ol < 4; ++ol){
      int ocl = g * 4 + ol;
      float a = sb[ocl];
      const float* wp_ = &sw[ocl * 36];
      #pragma unroll
      for (int u = 0; u < 36; ++u) a = fmaf(wp_[u], win[u], a);
      o[ol] = a;
    }
    outp[g * 2]     = (unsigned)f2bf(o[0]) | ((unsigned)f2bf(o[1]) << 16);
    outp[g * 2 + 1] = (unsigned)f2bf(o[2]) | ((unsigned)f2bf(o[3]) << 16);
  }
  size_t obase = (((size_t)b * 128 + hp0 + hpl) * 128 + wp0 + wpl) * 768 + ch0;
  #pragma unroll
  for (int c6 = 0; c6 < 6; ++c6){
    u32x4 v = { outp[c6 * 4], outp[c6 * 4 + 1], outp[c6 * 4 + 2], outp[c6 * 4 + 3] };
    *(u32x4*)&sum[obase + c6 * 8] = v;
  }
}

// ---------------------------------------------------------------------------
// hg GEMM (one side per launch), validated round 5.
// ---------------------------------------------------------------------------
__global__ __launch_bounds__(256) void k_hg(const unsigned short* __restrict__ cl,
    const unsigned short* __restrict__ Agr, unsigned short* __restrict__ hg,
    int side){
  __shared__ char lds[46592];             // A [96][208B]=19968 | B [128][208B]
  int t = threadIdx.x, lane = t & 63, wid = t >> 6;
  int head = blockIdx.z;
  int M0 = blockIdx.y * 96;
  size_t N0 = (size_t)blockIdx.x * 128;
  for (int i = t; i < 1152; i += 256){
    int m = i / 12, c = i % 12;
    u32x4 v = *(const u32x4*)&Agr[((size_t)side * 192 + M0 + m) * 96 + c * 8];
    *(u32x4*)(lds + m * 208 + c * 16) = v;
  }
  for (int i = t; i < 1536; i += 256){
    int px = i / 12, c = i % 12;
    u32x4 v = *(const u32x4*)&cl[(N0 + px) * 768 + side * 384 + head * 96 + c * 8];
    *(u32x4*)(lds + 19968 + px * 208 + c * 16) = v;
  }
  __syncthreads();
  f32x4 acc[6][2];
  #pragma unroll
  for (int i = 0; i < 6; ++i)
    #pragma unroll
    for (int j = 0; j < 2; ++j) acc[i][j] = (f32x4){0.f, 0.f, 0.f, 0.f};
  #pragma unroll
  for (int ks = 0; ks < 3; ++ks){
    short8 af[6], bfr[2];
    #pragma unroll
    for (int mf = 0; mf < 6; ++mf)
      af[mf] = *(const short8*)(lds + (mf * 16 + (lane & 15)) * 208 + ks * 64 + (lane >> 4) * 16);
    #pragma unroll
    for (int nf = 0; nf < 2; ++nf)
      bfr[nf] = *(const short8*)(lds + 19968 + (wid * 32 + nf * 16 + (lane & 15)) * 208 + ks * 64 + (lane >> 4) * 16);
    #pragma unroll
    for (int mf = 0; mf < 6; ++mf)
      #pragma unroll
      for (int nf = 0; nf < 2; ++nf)
        acc[mf][nf] = __builtin_amdgcn_mfma_f32_16x16x32_bf16(af[mf], bfr[nf], acc[mf][nf], 0, 0, 0);
  }
  #pragma unroll
  for (int mf = 0; mf < 6; ++mf)
    #pragma unroll
    for (int nf = 0; nf < 2; ++nf){
      int m = M0 + mf * 16 + ((lane >> 4) << 2);
      size_t px = N0 + wid * 32 + nf * 16 + (lane & 15);
      int b = (int)(px >> 14); size_t pxl = px & 16383;
      size_t base = (((size_t)b * 4 + head) * 16384 + pxl) * 192 + m;
      unsigned p0 = (unsigned)f2bf(acc[mf][nf][0]) | ((unsigned)f2bf(acc[mf][nf][1]) << 16);
      unsigned p1 = (unsigned)f2bf(acc[mf][nf][2]) | ((unsigned)f2bf(acc[mf][nf][3]) << 16);
      unsigned long long pp = (unsigned long long)p0 | ((unsigned long long)p1 << 32);
      *(unsigned long long*)&hg[base] = pp;
    }
}

// ---------------------------------------------------------------------------
// minGRU recurrence (one side per launch), validated round 5.
// ---------------------------------------------------------------------------
__global__ __launch_bounds__(192) void k_scan2(const unsigned short* __restrict__ hg,
                                               unsigned short* __restrict__ sum,
                                               int side){
  int bid = blockIdx.x;
  int xq = bid & 63, head = (bid >> 6) & 3, b = bid >> 8;
  int t = threadIdx.x;
  int d = t % 96, xl = t / 96;
  int x = xq * 2 + xl;
  const unsigned short* hb = &hg[(((size_t)b * 4 + head) * 16384) * 192];
  float h = 0.f;
  for (int step = 0; step < 128; ++step){
    int pxl = side ? (x * 128 + step) : (step * 128 + x);
    float hid = bf2f(hb[(size_t)pxl * 192 + d]);
    float gat = bf2f(hb[(size_t)pxl * 192 + 96 + d]);
    float z  = 1.f / (1.f + __expf(-gat));
    float th = hid >= 0.f ? hid + 0.5f : 1.f / (1.f + __expf(-hid));
    h += z * (th - h);
    size_t o = ((size_t)b * 16384 + pxl) * 768 + side * 384 + head * 96 + d;
    sum[o] = f2bf(bf2f(sum[o]) + h);
  }
}

// ---------------------------------------------------------------------------
// unpatch (validated round 4).
// ---------------------------------------------------------------------------
__global__ __launch_bounds__(256) void k_unpatch(const unsigned short* __restrict__ sum,
    const unsigned short* __restrict__ Aun, const float* __restrict__ bun,
    float* __restrict__ out){
  __shared__ char lds[53248];            // A [128][208B] | B [128][208B]
  int t = threadIdx.x, lane = t & 63;
  int wid = t >> 6, mw = wid >> 1, nw = wid & 1;
  int M0 = blockIdx.y * 128;
  size_t N0 = (size_t)blockIdx.x * 128;
  f32x4 acc[4][4];
  #pragma unroll
  for (int i = 0; i < 4; ++i)
    #pragma unroll
    for (int j = 0; j < 4; ++j) acc[i][j] = (f32x4){0.f, 0.f, 0.f, 0.f};
  for (int kc = 0; kc < 8; ++kc){
    __syncthreads();
    for (int i = t; i < 1536; i += 256){
      int m = i / 12, c = i % 12;
      u32x4 v = *(const u32x4*)&Aun[(size_t)(M0 + m) * 768 + kc * 96 + c * 8];
      *(u32x4*)(lds + m * 208 + c * 16) = v;
    }
    for (int i = t; i < 1536; i += 256){
      int px = i / 12, c = i % 12;
      u32x4 v = *(const u32x4*)&sum[(N0 + px) * 768 + kc * 96 + c * 8];
      *(u32x4*)(lds + 26624 + px * 208 + c * 16) = v;
    }
    __syncthreads();
    #pragma unroll
    for (int ks = 0; ks < 3; ++ks){
      short8 af[4], bfr[4];
      #pragma unroll
      for (int mf = 0; mf < 4; ++mf)
        af[mf] = *(const short8*)(lds + (mw * 64 + mf * 16 + (lane & 15)) * 208 + ks * 64 + (lane >> 4) * 16);
      #pragma unroll
      for (int nf = 0; nf < 4; ++nf)
        bfr[nf] = *(const short8*)(lds + 26624 + (nw * 64 + nf * 16 + (lane & 15)) * 208 + ks * 64 + (lane >> 4) * 16);
      #pragma unroll
      for (int mf = 0; mf < 4; ++mf)
        #pragma unroll
        for (int nf = 0; nf < 4; ++nf)
          acc[mf][nf] = __builtin_amdgcn_mfma_f32_16x16x32_bf16(af[mf], bfr[nf], acc[mf][nf], 0, 0, 0);
    }
  }
  #pragma unroll
  for (int mf = 0; mf < 4; ++mf)
    #pragma unroll
    for (int nf = 0; nf < 4; ++nf)
      #pragma unroll
      for (int j = 0; j < 4; ++j){
        int m = M0 + mw * 64 + mf * 16 + (lane >> 4) * 4 + j;
        int co = m >> 2, p = (m >> 1) & 1, q = m & 1;
        size_t px = N0 + nw * 64 + nf * 16 + (lane & 15);
        int b = (int)(px >> 14); int pxl = (int)(px & 16383);
        int hp = pxl >> 7, wp = pxl & 127;
        out[(((size_t)b * 96 + co) * 256 + 2 * hp + p) * 256 + 2 * wp + q] = acc[mf][nf][j] + bun[co];
      }
}

// ---------------------------------------------------------------------------
extern "C" void kernel_launch(void* const* d_in, const int* in_sizes, int n_in,
                              void* d_out, int out_size, void* d_ws, size_t ws_size,
                              hipStream_t stream){
  (void)in_sizes; (void)n_in; (void)out_size;
  const float* x    = (const float*)d_in[0];
  const float* rpw  = (const float*)d_in[1];
  const float* rpb  = (const float*)d_in[2];
  const float* cpw  = (const float*)d_in[3];
  const float* cpb  = (const float*)d_in[4];
  const float* rpew = (const float*)d_in[5];
  const float* rpeb = (const float*)d_in[6];
  const float* cpew = (const float*)d_in[7];
  const float* cpeb = (const float*)d_in[8];
  const float* runw = (const float*)d_in[9];
  const float* runb = (const float*)d_in[10];
  const float* cunw = (const float*)d_in[11];
  const float* cunb = (const float*)d_in[12];
  const float* rgw  = (const float*)d_in[13];
  const float* cgw  = (const float*)d_in[14];

  char* ws = (char*)d_ws;
  const size_t SZ_XT   = (size_t)8 * 260 * 260 * 128 * 2;   // 138,444,800
  const size_t OFF_A2  = SZ_XT;
  const size_t SZ_A2   = (size_t)768 * 2400 * 2;
  const size_t OFF_AUN = OFF_A2 + SZ_A2;
  const size_t SZ_AUN  = (size_t)384 * 768 * 2;
  const size_t OFF_AGR = OFF_AUN + SZ_AUN;
  const size_t SZ_AGR  = (size_t)2 * 192 * 96 * 2;
  const size_t OFF_BUN = OFF_AGR + SZ_AGR;
  const size_t OFF_HG  = ((OFF_BUN + 384) + 255) & ~(size_t)255;
  const size_t SZ_PL   = (size_t)8 * 768 * 128 * 128 * 2;   // 201,326,592
  const size_t OFF_CL  = OFF_HG + SZ_PL;
  const size_t OFF_SUM = OFF_CL + SZ_PL;
  const size_t NEED    = OFF_SUM + SZ_PL;                   // ~747 MB
  if (ws_size < NEED){
    fprintf(stderr, "kernel_launch: ws_size %zu < needed %zu\n", ws_size, NEED);
    return;
  }
  unsigned short* xt  = (unsigned short*)(ws);
  unsigned short* A2  = (unsigned short*)(ws + OFF_A2);
  unsigned short* Aun = (unsigned short*)(ws + OFF_AUN);
  unsigned short* Agr = (unsigned short*)(ws + OFF_AGR);
  float*          bun = (float*)(ws + OFF_BUN);
  unsigned short* hg  = (unsigned short*)(ws + OFF_HG);  // per-side hg scratch
  unsigned short* cl  = (unsigned short*)(ws + OFF_CL);
  unsigned short* sum = (unsigned short*)(ws + OFF_SUM);
  float* out = (float*)d_out;

  hipMemsetAsync(xt, 0, SZ_XT, stream);
  k_xt  <<<dim3(8192),       dim3(256), 0, stream>>>(x, xt);
  k_pack<<<dim3(8497),       dim3(256), 0, stream>>>(rpw, cpw, runw, cunw, runb, cunb, rgw, cgw, A2, Aun, Agr, bun);
  k_conv<<<dim3(512, 6),     dim3(512), 0, stream>>>(xt, A2, rpb, cpb, cl);
  k_pe  <<<dim3(8192),       dim3(256), 0, stream>>>(cl, rpew, cpew, rpeb, cpeb, sum);
  k_hg   <<<dim3(1024, 2, 4),dim3(256), 0, stream>>>(cl, Agr, hg, 0);
  k_scan2<<<dim3(2048),      dim3(192), 0, stream>>>(hg, sum, 0);
  k_hg   <<<dim3(1024, 2, 4),dim3(256), 0, stream>>>(cl, Agr, hg, 1);
  k_scan2<<<dim3(2048),      dim3(192), 0, stream>>>(hg, sum, 1);
  k_unpatch<<<dim3(1024, 3), dim3(256), 0, stream>>>(sum, Aun, bun, out);
}

// Round 11
// 2171.829 us; speedup vs baseline: 1.1083x; 1.1083x over previous
//
#include <hip/hip_runtime.h>
#include <stdint.h>
#include <stdio.h>

typedef __attribute__((ext_vector_type(8))) short short8;
typedef __attribute__((ext_vector_type(4))) float f32x4;
typedef __attribute__((ext_vector_type(4))) unsigned int u32x4;

#define DEV static __device__ __forceinline__

DEV unsigned short f2bf(float f){
  unsigned u = __float_as_uint(f);
  u += 0x7FFFu + ((u >> 16) & 1u);          // RNE
  return (unsigned short)(u >> 16);
}
DEV float bf2f(unsigned short h){ return __uint_as_float(((unsigned)h) << 16); }

// ---------------------------------------------------------------------------
// x (8,96,256,256) f32  ->  xt (8,260,260,128) bf16 channels-last with halo=2
// ---------------------------------------------------------------------------
__global__ __launch_bounds__(256) void k_xt(const float* __restrict__ x,
                                            unsigned short* __restrict__ xt){
  int bid = blockIdx.x;                 // 8*256*4
  int wq = bid & 3, h = (bid >> 2) & 255, b = bid >> 10;
  int w0 = wq * 64;
  __shared__ unsigned short s[64 * 104];
  int t = threadIdx.x;
  int wl = t & 63, cq = t >> 6;         // cq 0..3
  const float* xp = x + ((size_t)b * 96 * 256 + h) * 256 + w0 + wl;
  #pragma unroll
  for (int i = 0; i < 24; ++i){
    int c = cq + i * 4;                 // 0..95
    s[wl * 104 + c] = f2bf(xp[(size_t)c * 65536]);
  }
  __syncthreads();
  unsigned short* dst = xt + (((size_t)b * 260 + h + 2) * 260 + (w0 + 2)) * 128;
  #pragma unroll
  for (int p = 0; p < 3; ++p){
    int i = t + p * 256;                // 0..767 = 64 w * 12 chunks
    int w = i / 12, ch = i % 12;
    u32x4 v = *(const u32x4*)&s[w * 104 + ch * 8];
    *(u32x4*)&dst[(size_t)w * 128 + ch * 8] = v;
  }
}

// ---------------------------------------------------------------------------
// weight repack (bf16):
//  A2  [768][ (kh*5+kw)*96 + ic ]   patch-conv weights (r then c)
//  Aun [m=co*4+p*2+q][ci 0..767]    unpatch weights
//  Agr [side][m 0..191][k 0..95]    gru weights transposed
//  bun [96] f32 = r_un_b + c_un_b
// ---------------------------------------------------------------------------
__global__ __launch_bounds__(256) void k_pack(const float* __restrict__ rpw, const float* __restrict__ cpw,
    const float* __restrict__ runw, const float* __restrict__ cunw,
    const float* __restrict__ runb, const float* __restrict__ cunb,
    const float* __restrict__ rgw,  const float* __restrict__ cgw,
    unsigned short* __restrict__ A2, unsigned short* __restrict__ Aun,
    unsigned short* __restrict__ Agr, float* __restrict__ bun){
  int tid = blockIdx.x * 256 + threadIdx.x;
  const int NA2 = 768 * 2400, NUN = 384 * 768, NGR = 2 * 192 * 96;
  if (tid < NA2){
    int oc = tid / 2400, r = tid % 2400;
    int kh = r / 480, kw = (r / 96) % 5, ic = r % 96;
    const float* W = oc < 384 ? rpw : cpw;
    int o = oc < 384 ? oc : oc - 384;
    A2[tid] = f2bf(W[(((size_t)o * 96 + ic) * 5 + kh) * 5 + kw]);
  } else if (tid < NA2 + NUN){
    int i = tid - NA2;
    int m = i / 768, ci = i % 768;
    int co = m >> 2, p = (m >> 1) & 1, q = m & 1;
    const float* W = ci < 384 ? runw : cunw;
    int c = ci < 384 ? ci : ci - 384;
    Aun[i] = f2bf(W[(((size_t)c * 96 + co) * 2 + p) * 2 + q]);
  } else if (tid < NA2 + NUN + NGR){
    int i = tid - NA2 - NUN;
    int side = i / 18432, r = i % 18432;
    int m = r / 96, k = r % 96;
    const float* W = side ? cgw : rgw;       // (96,192) row-major
    Agr[i] = f2bf(W[k * 192 + m]);
  } else if (tid < NA2 + NUN + NGR + 96){
    int co = tid - NA2 - NUN - NGR;
    bun[co] = runb[co] + cunb[co];
  }
}

// ---------------------------------------------------------------------------
// patch conv as implicit GEMM, v7 = v6b + XCD-grouped grid + epilogue swizzle.
// 1D grid 3072: bid = xcd + 8*(6*pgrp + m) -> the 6 M-tiles of one pixel
// tile are consecutive on the SAME XCD (B-tile L2 reuse, ~6x fetch cut).
// Epilogue S-write swizzled (oc ^ ((px&7)<<3)): 16-way -> 2-way conflicts.
// ---------------------------------------------------------------------------
__global__ __launch_bounds__(512) void k_conv(const unsigned short* __restrict__ xt,
    const unsigned short* __restrict__ A2,
    const float* __restrict__ rpb, const float* __restrict__ cpb,
    unsigned short* __restrict__ cl){
  __shared__ char lds[160768];
  const int BOFF = 26624;               // B region offset
  const int BPITCH = 33536;             // 131 cols * 256 B
  const int BITEMS = 8384;              // 4 rows * 131 cols * 16 ch
  int t = threadIdx.x, lane = t & 63;
  int wid = t >> 6, mw = wid >> 2, nw = wid & 3;
  int wl = lane & 15, cg = lane >> 4;
  int bid = blockIdx.x;                 // 3072 = 8 xcd * (64 pgrp * 6 m)
  int xcd = bid & 7, rr = bid >> 3;
  int mt = rr % 6, pgrp = rr / 6;
  int p = pgrp * 8 + xcd;               // pixel tile 0..511
  int wq = p & 1, hq = (p >> 1) & 31, b = p >> 6;
  int ho0 = hq * 4, wo0 = wq * 64;
  int M0 = mt * 128;

  // A staging role: oc = t>>2 (0..127), quarter = t&3 (24 elems each)
  int a_oc = t >> 2, a_q = t & 3;
  const unsigned short* Aoc = A2 + (size_t)(M0 + a_oc) * 2400 + a_q * 24;
  char* Adst = lds + a_oc * 208 + a_q * 48;

  f32x4 acc[4][4];
  #pragma unroll
  for (int i = 0; i < 4; ++i)
    #pragma unroll
    for (int j = 0; j < 4; ++j) acc[i][j] = (f32x4){0.f, 0.f, 0.f, 0.f};

  u32x4 aR[3], bR[17];
  // ---- prologue: A(0,0) + B(kh=0) ----
  #pragma unroll
  for (int c = 0; c < 3; ++c) aR[c] = *(const u32x4*)(Aoc + c * 8);
  #pragma unroll
  for (int it = 0; it < 17; ++it){
    int i = t + it * 512;
    if (i < BITEMS){
      int row = i / 2096, j = i % 2096, col = j >> 4, ch = j & 15;
      bR[it] = *(const u32x4*)&xt[(((size_t)b * 260 + 2 * ho0 + 2 * row) * 260 + 2 * wo0 + col) * 128 + ch * 8];
    }
  }
  #pragma unroll
  for (int c = 0; c < 3; ++c) *(u32x4*)(Adst + c * 16) = aR[c];
  #pragma unroll
  for (int it = 0; it < 17; ++it){
    int i = t + it * 512;
    if (i < BITEMS){
      int row = i / 2096, j = i % 2096, col = j >> 4, ch = j & 15;
      *(u32x4*)(lds + BOFF + row * BPITCH + col * 256 + (ch ^ ((col >> 1) & 7)) * 16) = bR[it];
    }
  }
  __syncthreads();

  for (int kh = 0; kh < 5; ++kh){
    #pragma unroll
    for (int kw = 0; kw < 5; ++kw){
      bool last = (kh == 4 && kw == 4);
      bool khb  = (kw == 4 && kh < 4);
      // issue next-slab A prefetch (global -> regs)
      if (!last){
        int nkh = kh + (kw == 4 ? 1 : 0), nkw = (kw == 4 ? 0 : kw + 1);
        const unsigned short* As = Aoc + (nkh * 5 + nkw) * 96;
        #pragma unroll
        for (int c = 0; c < 3; ++c) aR[c] = *(const u32x4*)(As + c * 8);
      }
      // issue next-kh B prefetch (global -> regs), hidden under 48 MFMA
      if (khb){
        #pragma unroll
        for (int it = 0; it < 17; ++it){
          int i = t + it * 512;
          if (i < BITEMS){
            int row = i / 2096, j = i % 2096, col = j >> 4, ch = j & 15;
            bR[it] = *(const u32x4*)&xt[(((size_t)b * 260 + 2 * ho0 + 2 * row + kh + 1) * 260 + 2 * wo0 + col) * 128 + ch * 8];
          }
        }
      }
      // ---- compute slab (kh,kw): 48 MFMA per wave ----
      {
        int col = 32 * nw + 2 * wl + kw;
        int sx = (col >> 1) & 7;
        #pragma unroll
        for (int ics = 0; ics < 3; ++ics){
          short8 af[4], bfr[4];
          #pragma unroll
          for (int mf = 0; mf < 4; ++mf)
            af[mf] = *(const short8*)(lds + (mw * 64 + mf * 16 + wl) * 208 + ics * 64 + cg * 16);
          int chl = (ics * 4 + cg) ^ sx;
          #pragma unroll
          for (int nf = 0; nf < 4; ++nf)
            bfr[nf] = *(const short8*)(lds + BOFF + nf * BPITCH + col * 256 + chl * 16);
          #pragma unroll
          for (int mf = 0; mf < 4; ++mf)
            #pragma unroll
            for (int nf = 0; nf < 4; ++nf)
              acc[mf][nf] = __builtin_amdgcn_mfma_f32_16x16x32_bf16(af[mf], bfr[nf], acc[mf][nf], 0, 0, 0);
        }
      }
      __syncthreads();                  // all waves done reading A/B
      if (!last){
        #pragma unroll
        for (int c = 0; c < 3; ++c) *(u32x4*)(Adst + c * 16) = aR[c];
        if (khb){
          #pragma unroll
          for (int it = 0; it < 17; ++it){
            int i = t + it * 512;
            if (i < BITEMS){
              int row = i / 2096, j = i % 2096, col = j >> 4, ch = j & 15;
              *(u32x4*)(lds + BOFF + row * BPITCH + col * 256 + (ch ^ ((col >> 1) & 7)) * 16) = bR[it];
            }
          }
        }
      }
      __syncthreads();                  // staged data visible
    }
  }
  // epilogue: bias, stash to LDS [256 px][128 oc] (swizzled), coop cl write
  unsigned short* S = (unsigned short*)lds;
  #pragma unroll
  for (int mf = 0; mf < 4; ++mf)
    #pragma unroll
    for (int nf = 0; nf < 4; ++nf){
      int wol = nw * 16 + wl;
      int pxl = nf * 64 + wol;
      int sw8 = (pxl & 7) << 3;
      #pragma unroll
      for (int j = 0; j < 4; ++j){
        int ocl = mw * 64 + mf * 16 + cg * 4 + j;
        int oc = M0 + ocl;
        float v = acc[mf][nf][j] + (oc < 384 ? rpb[oc] : cpb[oc - 384]);
        S[pxl * 128 + (ocl ^ sw8)] = f2bf(v);
      }
    }
  __syncthreads();
  #pragma unroll
  for (int it = 0; it < 8; ++it){
    int i = t + it * 512;               // 0..4095 = 256 px * 16 chunks
    int pxl = i >> 4, ch = i & 15;
    int chs = ch ^ (pxl & 7);
    int ho = ho0 + (pxl >> 6), wo = wo0 + (pxl & 63);
    u32x4 v = *(const u32x4*)&S[pxl * 128 + chs * 8];
    *(u32x4*)&cl[(((size_t)b * 128 + ho) * 128 + wo) * 768 + M0 + ch * 8] = v;
  }
}

// ---------------------------------------------------------------------------
// positional grouped conv 3x3 (groups of 4ch), reading channels-last cl.
// ---------------------------------------------------------------------------
__global__ __launch_bounds__(256) void k_pe(const unsigned short* __restrict__ cl,
    const float* __restrict__ rpew, const float* __restrict__ cpew,
    const float* __restrict__ rpeb, const float* __restrict__ cpeb,
    unsigned short* __restrict__ sum){
  __shared__ unsigned short si[48 * 340];  // [48 ch][10 r][34 c]
  __shared__ float sw[48 * 36];
  __shared__ float sb[48];
  int bid = blockIdx.x;                    // 8*16*16*4
  int wq = bid & 3, hq = (bid >> 2) & 15, slab = (bid >> 6) & 15, b = bid >> 10;
  int ch0 = slab * 48, hp0 = hq * 8, wp0 = wq * 32;
  int t = threadIdx.x;
  for (int i = t; i < 48 * 36; i += 256){
    int ocl = i / 36, r = i % 36;
    int oc = ch0 + ocl;
    const float* W = oc < 384 ? rpew : cpew;
    int o = oc < 384 ? oc : oc - 384;
    sw[i] = W[(size_t)o * 36 + r];
  }
  if (t < 48){
    int oc = ch0 + t;
    sb[t] = oc < 384 ? rpeb[oc] : cpeb[oc - 384];
  }
  for (int i = t; i < 340 * 48; i += 256){   // pixel-major: 48ch contiguous
    int pix = i / 48, c = i % 48;
    int r2 = pix / 34, cc = pix % 34;
    int hp = hp0 - 1 + r2, wp = wp0 - 1 + cc;
    unsigned short v = 0;
    if (hp >= 0 && hp < 128 && wp >= 0 && wp < 128)
      v = cl[((size_t)b * 16384 + hp * 128 + wp) * 768 + ch0 + c];
    si[c * 340 + pix] = v;
  }
  __syncthreads();
  int hpl = t >> 5, wpl = t & 31;
  unsigned int outp[24];
  #pragma unroll
  for (int g = 0; g < 12; ++g){
    float win[36];
    #pragma unroll
    for (int ii = 0; ii < 4; ++ii)
      #pragma unroll
      for (int dh = 0; dh < 3; ++dh)
        #pragma unroll
        for (int dw = 0; dw < 3; ++dw)
          win[ii * 9 + dh * 3 + dw] = bf2f(si[(g * 4 + ii) * 340 + (hpl + dh) * 34 + (wpl + dw)]);
    float o[4];
    #pragma unroll
    for (int ol = 0; ol < 4; ++ol){
      int ocl = g * 4 + ol;
      float a = sb[ocl];
      const float* wp_ = &sw[ocl * 36];
      #pragma unroll
      for (int u = 0; u < 36; ++u) a = fmaf(wp_[u], win[u], a);
      o[ol] = a;
    }
    outp[g * 2]     = (unsigned)f2bf(o[0]) | ((unsigned)f2bf(o[1]) << 16);
    outp[g * 2 + 1] = (unsigned)f2bf(o[2]) | ((unsigned)f2bf(o[3]) << 16);
  }
  size_t obase = (((size_t)b * 128 + hp0 + hpl) * 128 + wp0 + wpl) * 768 + ch0;
  #pragma unroll
  for (int c6 = 0; c6 < 6; ++c6){
    u32x4 v = { outp[c6 * 4], outp[c6 * 4 + 1], outp[c6 * 4 + 2], outp[c6 * 4 + 3] };
    *(u32x4*)&sum[obase + c6 * 8] = v;
  }
}

// ---------------------------------------------------------------------------
// hg GEMM (one side per launch), v2: full M=192 in one block (cl read once).
// grid (1024 px, 1, 4 heads); 4 waves, wave = 192m x 32px, K=96 (3 steps).
// LDS: A [192][208B]=39936 | B [128][208B]=26624 -> 66560, 2 blocks/CU.
// ---------------------------------------------------------------------------
__global__ __launch_bounds__(256) void k_hg(const unsigned short* __restrict__ cl,
    const unsigned short* __restrict__ Agr, unsigned short* __restrict__ hg,
    int side){
  __shared__ char lds[66560];
  int t = threadIdx.x, lane = t & 63, wid = t >> 6;
  int head = blockIdx.z;
  size_t N0 = (size_t)blockIdx.x * 128;
  for (int i = t; i < 2304; i += 256){
    int m = i / 12, c = i % 12;
    u32x4 v = *(const u32x4*)&Agr[((size_t)side * 192 + m) * 96 + c * 8];
    *(u32x4*)(lds + m * 208 + c * 16) = v;
  }
  for (int i = t; i < 1536; i += 256){
    int px = i / 12, c = i % 12;
    u32x4 v = *(const u32x4*)&cl[(N0 + px) * 768 + side * 384 + head * 96 + c * 8];
    *(u32x4*)(lds + 39936 + px * 208 + c * 16) = v;
  }
  __syncthreads();
  f32x4 acc[12][2];
  #pragma unroll
  for (int i = 0; i < 12; ++i)
    #pragma unroll
    for (int j = 0; j < 2; ++j) acc[i][j] = (f32x4){0.f, 0.f, 0.f, 0.f};
  #pragma unroll
  for (int ks = 0; ks < 3; ++ks){
    short8 af[12], bfr[2];
    #pragma unroll
    for (int mf = 0; mf < 12; ++mf)
      af[mf] = *(const short8*)(lds + (mf * 16 + (lane & 15)) * 208 + ks * 64 + (lane >> 4) * 16);
    #pragma unroll
    for (int nf = 0; nf < 2; ++nf)
      bfr[nf] = *(const short8*)(lds + 39936 + (wid * 32 + nf * 16 + (lane & 15)) * 208 + ks * 64 + (lane >> 4) * 16);
    #pragma unroll
    for (int mf = 0; mf < 12; ++mf)
      #pragma unroll
      for (int nf = 0; nf < 2; ++nf)
        acc[mf][nf] = __builtin_amdgcn_mfma_f32_16x16x32_bf16(af[mf], bfr[nf], acc[mf][nf], 0, 0, 0);
  }
  #pragma unroll
  for (int mf = 0; mf < 12; ++mf)
    #pragma unroll
    for (int nf = 0; nf < 2; ++nf){
      int m = mf * 16 + ((lane >> 4) << 2);
      size_t px = N0 + wid * 32 + nf * 16 + (lane & 15);
      int b = (int)(px >> 14); size_t pxl = px & 16383;
      size_t base = (((size_t)b * 4 + head) * 16384 + pxl) * 192 + m;
      unsigned p0 = (unsigned)f2bf(acc[mf][nf][0]) | ((unsigned)f2bf(acc[mf][nf][1]) << 16);
      unsigned p1 = (unsigned)f2bf(acc[mf][nf][2]) | ((unsigned)f2bf(acc[mf][nf][3]) << 16);
      unsigned long long pp = (unsigned long long)p0 | ((unsigned long long)p1 << 32);
      *(unsigned long long*)&hg[base] = pp;
    }
}

// ---------------------------------------------------------------------------
// minGRU recurrence (one side per launch), validated round 5.
// ---------------------------------------------------------------------------
__global__ __launch_bounds__(192) void k_scan2(const unsigned short* __restrict__ hg,
                                               unsigned short* __restrict__ sum,
                                               int side){
  int bid = blockIdx.x;
  int xq = bid & 63, head = (bid >> 6) & 3, b = bid >> 8;
  int t = threadIdx.x;
  int d = t % 96, xl = t / 96;
  int x = xq * 2 + xl;
  const unsigned short* hb = &hg[(((size_t)b * 4 + head) * 16384) * 192];
  float h = 0.f;
  for (int step = 0; step < 128; ++step){
    int pxl = side ? (x * 128 + step) : (step * 128 + x);
    float hid = bf2f(hb[(size_t)pxl * 192 + d]);
    float gat = bf2f(hb[(size_t)pxl * 192 + 96 + d]);
    float z  = 1.f / (1.f + __expf(-gat));
    float th = hid >= 0.f ? hid + 0.5f : 1.f / (1.f + __expf(-hid));
    h += z * (th - h);
    size_t o = ((size_t)b * 16384 + pxl) * 768 + side * 384 + head * 96 + d;
    sum[o] = f2bf(bf2f(sum[o]) + h);
  }
}

// ---------------------------------------------------------------------------
// unpatch, v2: XCD-grouped 1D grid (3 M-tiles of one px tile on same XCD).
// ---------------------------------------------------------------------------
__global__ __launch_bounds__(256) void k_unpatch(const unsigned short* __restrict__ sum,
    const unsigned short* __restrict__ Aun, const float* __restrict__ bun,
    float* __restrict__ out){
  __shared__ char lds[53248];            // A [128][208B] | B [128][208B]
  int t = threadIdx.x, lane = t & 63;
  int wid = t >> 6, mw = wid >> 1, nw = wid & 1;
  int bid = blockIdx.x;                  // 3072 = 8 xcd * (128 pgrp * 3 m)
  int xcd = bid & 7, rr = bid >> 3;
  int mt = rr % 3, pgrp = rr / 3;
  int M0 = mt * 128;
  size_t N0 = (size_t)(pgrp * 8 + xcd) * 128;
  f32x4 acc[4][4];
  #pragma unroll
  for (int i = 0; i < 4; ++i)
    #pragma unroll
    for (int j = 0; j < 4; ++j) acc[i][j] = (f32x4){0.f, 0.f, 0.f, 0.f};
  for (int kc = 0; kc < 8; ++kc){
    __syncthreads();
    for (int i = t; i < 1536; i += 256){
      int m = i / 12, c = i % 12;
      u32x4 v = *(const u32x4*)&Aun[(size_t)(M0 + m) * 768 + kc * 96 + c * 8];
      *(u32x4*)(lds + m * 208 + c * 16) = v;
    }
    for (int i = t; i < 1536; i += 256){
      int px = i / 12, c = i % 12;
      u32x4 v = *(const u32x4*)&sum[(N0 + px) * 768 + kc * 96 + c * 8];
      *(u32x4*)(lds + 26624 + px * 208 + c * 16) = v;
    }
    __syncthreads();
    #pragma unroll
    for (int ks = 0; ks < 3; ++ks){
      short8 af[4], bfr[4];
      #pragma unroll
      for (int mf = 0; mf < 4; ++mf)
        af[mf] = *(const short8*)(lds + (mw * 64 + mf * 16 + (lane & 15)) * 208 + ks * 64 + (lane >> 4) * 16);
      #pragma unroll
      for (int nf = 0; nf < 4; ++nf)
        bfr[nf] = *(const short8*)(lds + 26624 + (nw * 64 + nf * 16 + (lane & 15)) * 208 + ks * 64 + (lane >> 4) * 16);
      #pragma unroll
      for (int mf = 0; mf < 4; ++mf)
        #pragma unroll
        for (int nf = 0; nf < 4; ++nf)
          acc[mf][nf] = __builtin_amdgcn_mfma_f32_16x16x32_bf16(af[mf], bfr[nf], acc[mf][nf], 0, 0, 0);
    }
  }
  #pragma unroll
  for (int mf = 0; mf < 4; ++mf)
    #pragma unroll
    for (int nf = 0; nf < 4; ++nf)
      #pragma unroll
      for (int j = 0; j < 4; ++j){
        int m = M0 + mw * 64 + mf * 16 + (lane >> 4) * 4 + j;
        int co = m >> 2, p = (m >> 1) & 1, q = m & 1;
        size_t px = N0 + nw * 64 + nf * 16 + (lane & 15);
        int b = (int)(px >> 14); int pxl = (int)(px & 16383);
        int hp = pxl >> 7, wp = pxl & 127;
        out[(((size_t)b * 96 + co) * 256 + 2 * hp + p) * 256 + 2 * wp + q] = acc[mf][nf][j] + bun[co];
      }
}

// ---------------------------------------------------------------------------
extern "C" void kernel_launch(void* const* d_in, const int* in_sizes, int n_in,
                              void* d_out, int out_size, void* d_ws, size_t ws_size,
                              hipStream_t stream){
  (void)in_sizes; (void)n_in; (void)out_size;
  const float* x    = (const float*)d_in[0];
  const float* rpw  = (const float*)d_in[1];
  const float* rpb  = (const float*)d_in[2];
  const float* cpw  = (const float*)d_in[3];
  const float* cpb  = (const float*)d_in[4];
  const float* rpew = (const float*)d_in[5];
  const float* rpeb = (const float*)d_in[6];
  const float* cpew = (const float*)d_in[7];
  const float* cpeb = (const float*)d_in[8];
  const float* runw = (const float*)d_in[9];
  const float* runb = (const float*)d_in[10];
  const float* cunw = (const float*)d_in[11];
  const float* cunb = (const float*)d_in[12];
  const float* rgw  = (const float*)d_in[13];
  const float* cgw  = (const float*)d_in[14];

  char* ws = (char*)d_ws;
  const size_t SZ_XT   = (size_t)8 * 260 * 260 * 128 * 2;   // 138,444,800
  const size_t OFF_A2  = SZ_XT;
  const size_t SZ_A2   = (size_t)768 * 2400 * 2;
  const size_t OFF_AUN = OFF_A2 + SZ_A2;
  const size_t SZ_AUN  = (size_t)384 * 768 * 2;
  const size_t OFF_AGR = OFF_AUN + SZ_AUN;
  const size_t SZ_AGR  = (size_t)2 * 192 * 96 * 2;
  const size_t OFF_BUN = OFF_AGR + SZ_AGR;
  const size_t OFF_HG  = ((OFF_BUN + 384) + 255) & ~(size_t)255;
  const size_t SZ_PL   = (size_t)8 * 768 * 128 * 128 * 2;   // 201,326,592
  const size_t OFF_CL  = OFF_HG + SZ_PL;
  const size_t OFF_SUM = OFF_CL + SZ_PL;
  const size_t NEED    = OFF_SUM + SZ_PL;                   // ~747 MB
  if (ws_size < NEED){
    fprintf(stderr, "kernel_launch: ws_size %zu < needed %zu\n", ws_size, NEED);
    return;
  }
  unsigned short* xt  = (unsigned short*)(ws);
  unsigned short* A2  = (unsigned short*)(ws + OFF_A2);
  unsigned short* Aun = (unsigned short*)(ws + OFF_AUN);
  unsigned short* Agr = (unsigned short*)(ws + OFF_AGR);
  float*          bun = (float*)(ws + OFF_BUN);
  unsigned short* hg  = (unsigned short*)(ws + OFF_HG);  // per-side hg scratch
  unsigned short* cl  = (unsigned short*)(ws + OFF_CL);
  unsigned short* sum = (unsigned short*)(ws + OFF_SUM);
  float* out = (float*)d_out;

  hipMemsetAsync(xt, 0, SZ_XT, stream);
  k_xt  <<<dim3(8192),       dim3(256), 0, stream>>>(x, xt);
  k_pack<<<dim3(8497),       dim3(256), 0, stream>>>(rpw, cpw, runw, cunw, runb, cunb, rgw, cgw, A2, Aun, Agr, bun);
  k_conv<<<dim3(3072),       dim3(512), 0, stream>>>(xt, A2, rpb, cpb, cl);
  k_pe  <<<dim3(8192),       dim3(256), 0, stream>>>(cl, rpew, cpew, rpeb, cpeb, sum);
  k_hg   <<<dim3(1024, 1, 4),dim3(256), 0, stream>>>(cl, Agr, hg, 0);
  k_scan2<<<dim3(2048),      dim3(192), 0, stream>>>(hg, sum, 0);
  k_hg   <<<dim3(1024, 1, 4),dim3(256), 0, stream>>>(cl, Agr, hg, 1);
  k_scan2<<<dim3(2048),      dim3(192), 0, stream>>>(hg, sum, 1);
  k_unpatch<<<dim3(3072),    dim3(256), 0, stream>>>(sum, Aun, bun, out);
}

// Round 12
// 1689.676 us; speedup vs baseline: 1.4246x; 1.2854x over previous
//
#include <hip/hip_runtime.h>
#include <stdint.h>
#include <stdio.h>

typedef __attribute__((ext_vector_type(8))) short short8;
typedef __attribute__((ext_vector_type(4))) float f32x4;
typedef __attribute__((ext_vector_type(4))) unsigned int u32x4;
typedef __attribute__((ext_vector_type(4))) unsigned short u16x4;

#define DEV static __device__ __forceinline__

DEV unsigned short f2bf(float f){
  unsigned u = __float_as_uint(f);
  u += 0x7FFFu + ((u >> 16) & 1u);          // RNE
  return (unsigned short)(u >> 16);
}
DEV float bf2f(unsigned short h){ return __uint_as_float(((unsigned)h) << 16); }

// ---------------------------------------------------------------------------
// x (8,96,256,256) f32  ->  xt (8,260,260,128) bf16 channels-last with halo=2
// ---------------------------------------------------------------------------
__global__ __launch_bounds__(256) void k_xt(const float* __restrict__ x,
                                            unsigned short* __restrict__ xt){
  int bid = blockIdx.x;                 // 8*256*4
  int wq = bid & 3, h = (bid >> 2) & 255, b = bid >> 10;
  int w0 = wq * 64;
  __shared__ unsigned short s[64 * 104];
  int t = threadIdx.x;
  int wl = t & 63, cq = t >> 6;         // cq 0..3
  const float* xp = x + ((size_t)b * 96 * 256 + h) * 256 + w0 + wl;
  #pragma unroll
  for (int i = 0; i < 24; ++i){
    int c = cq + i * 4;                 // 0..95
    s[wl * 104 + c] = f2bf(xp[(size_t)c * 65536]);
  }
  __syncthreads();
  unsigned short* dst = xt + (((size_t)b * 260 + h + 2) * 260 + (w0 + 2)) * 128;
  #pragma unroll
  for (int p = 0; p < 3; ++p){
    int i = t + p * 256;                // 0..767 = 64 w * 12 chunks
    int w = i / 12, ch = i % 12;
    u32x4 v = *(const u32x4*)&s[w * 104 + ch * 8];
    *(u32x4*)&dst[(size_t)w * 128 + ch * 8] = v;
  }
}

// ---------------------------------------------------------------------------
// weight repack (bf16):
//  A2  [768][ (kh*5+kw)*96 + ic ]   patch-conv weights (r then c)
//  Aun [m=co*4+p*2+q][ci 0..767]    unpatch weights
//  Agr [side][m 0..191][k 0..95]    gru weights transposed
//  bun [96] f32 = r_un_b + c_un_b
// ---------------------------------------------------------------------------
__global__ __launch_bounds__(256) void k_pack(const float* __restrict__ rpw, const float* __restrict__ cpw,
    const float* __restrict__ runw, const float* __restrict__ cunw,
    const float* __restrict__ runb, const float* __restrict__ cunb,
    const float* __restrict__ rgw,  const float* __restrict__ cgw,
    unsigned short* __restrict__ A2, unsigned short* __restrict__ Aun,
    unsigned short* __restrict__ Agr, float* __restrict__ bun){
  int tid = blockIdx.x * 256 + threadIdx.x;
  const int NA2 = 768 * 2400, NUN = 384 * 768, NGR = 2 * 192 * 96;
  if (tid < NA2){
    int oc = tid / 2400, r = tid % 2400;
    int kh = r / 480, kw = (r / 96) % 5, ic = r % 96;
    const float* W = oc < 384 ? rpw : cpw;
    int o = oc < 384 ? oc : oc - 384;
    A2[tid] = f2bf(W[(((size_t)o * 96 + ic) * 5 + kh) * 5 + kw]);
  } else if (tid < NA2 + NUN){
    int i = tid - NA2;
    int m = i / 768, ci = i % 768;
    int co = m >> 2, p = (m >> 1) & 1, q = m & 1;
    const float* W = ci < 384 ? runw : cunw;
    int c = ci < 384 ? ci : ci - 384;
    Aun[i] = f2bf(W[(((size_t)c * 96 + co) * 2 + p) * 2 + q]);
  } else if (tid < NA2 + NUN + NGR){
    int i = tid - NA2 - NUN;
    int side = i / 18432, r = i % 18432;
    int m = r / 96, k = r % 96;
    const float* W = side ? cgw : rgw;       // (96,192) row-major
    Agr[i] = f2bf(W[k * 192 + m]);
  } else if (tid < NA2 + NUN + NGR + 96){
    int co = tid - NA2 - NUN - NGR;
    bun[co] = runb[co] + cunb[co];
  }
}

// ---------------------------------------------------------------------------
// patch conv as implicit GEMM, v7 (validated round 11).
// ---------------------------------------------------------------------------
__global__ __launch_bounds__(512) void k_conv(const unsigned short* __restrict__ xt,
    const unsigned short* __restrict__ A2,
    const float* __restrict__ rpb, const float* __restrict__ cpb,
    unsigned short* __restrict__ cl){
  __shared__ char lds[160768];
  const int BOFF = 26624;               // B region offset
  const int BPITCH = 33536;             // 131 cols * 256 B
  const int BITEMS = 8384;              // 4 rows * 131 cols * 16 ch
  int t = threadIdx.x, lane = t & 63;
  int wid = t >> 6, mw = wid >> 2, nw = wid & 3;
  int wl = lane & 15, cg = lane >> 4;
  int bid = blockIdx.x;                 // 3072 = 8 xcd * (64 pgrp * 6 m)
  int xcd = bid & 7, rr = bid >> 3;
  int mt = rr % 6, pgrp = rr / 6;
  int p = pgrp * 8 + xcd;               // pixel tile 0..511
  int wq = p & 1, hq = (p >> 1) & 31, b = p >> 6;
  int ho0 = hq * 4, wo0 = wq * 64;
  int M0 = mt * 128;

  int a_oc = t >> 2, a_q = t & 3;
  const unsigned short* Aoc = A2 + (size_t)(M0 + a_oc) * 2400 + a_q * 24;
  char* Adst = lds + a_oc * 208 + a_q * 48;

  f32x4 acc[4][4];
  #pragma unroll
  for (int i = 0; i < 4; ++i)
    #pragma unroll
    for (int j = 0; j < 4; ++j) acc[i][j] = (f32x4){0.f, 0.f, 0.f, 0.f};

  u32x4 aR[3], bR[17];
  #pragma unroll
  for (int c = 0; c < 3; ++c) aR[c] = *(const u32x4*)(Aoc + c * 8);
  #pragma unroll
  for (int it = 0; it < 17; ++it){
    int i = t + it * 512;
    if (i < BITEMS){
      int row = i / 2096, j = i % 2096, col = j >> 4, ch = j & 15;
      bR[it] = *(const u32x4*)&xt[(((size_t)b * 260 + 2 * ho0 + 2 * row) * 260 + 2 * wo0 + col) * 128 + ch * 8];
    }
  }
  #pragma unroll
  for (int c = 0; c < 3; ++c) *(u32x4*)(Adst + c * 16) = aR[c];
  #pragma unroll
  for (int it = 0; it < 17; ++it){
    int i = t + it * 512;
    if (i < BITEMS){
      int row = i / 2096, j = i % 2096, col = j >> 4, ch = j & 15;
      *(u32x4*)(lds + BOFF + row * BPITCH + col * 256 + (ch ^ ((col >> 1) & 7)) * 16) = bR[it];
    }
  }
  __syncthreads();

  for (int kh = 0; kh < 5; ++kh){
    #pragma unroll
    for (int kw = 0; kw < 5; ++kw){
      bool last = (kh == 4 && kw == 4);
      bool khb  = (kw == 4 && kh < 4);
      if (!last){
        int nkh = kh + (kw == 4 ? 1 : 0), nkw = (kw == 4 ? 0 : kw + 1);
        const unsigned short* As = Aoc + (nkh * 5 + nkw) * 96;
        #pragma unroll
        for (int c = 0; c < 3; ++c) aR[c] = *(const u32x4*)(As + c * 8);
      }
      if (khb){
        #pragma unroll
        for (int it = 0; it < 17; ++it){
          int i = t + it * 512;
          if (i < BITEMS){
            int row = i / 2096, j = i % 2096, col = j >> 4, ch = j & 15;
            bR[it] = *(const u32x4*)&xt[(((size_t)b * 260 + 2 * ho0 + 2 * row + kh + 1) * 260 + 2 * wo0 + col) * 128 + ch * 8];
          }
        }
      }
      {
        int col = 32 * nw + 2 * wl + kw;
        int sx = (col >> 1) & 7;
        #pragma unroll
        for (int ics = 0; ics < 3; ++ics){
          short8 af[4], bfr[4];
          #pragma unroll
          for (int mf = 0; mf < 4; ++mf)
            af[mf] = *(const short8*)(lds + (mw * 64 + mf * 16 + wl) * 208 + ics * 64 + cg * 16);
          int chl = (ics * 4 + cg) ^ sx;
          #pragma unroll
          for (int nf = 0; nf < 4; ++nf)
            bfr[nf] = *(const short8*)(lds + BOFF + nf * BPITCH + col * 256 + chl * 16);
          #pragma unroll
          for (int mf = 0; mf < 4; ++mf)
            #pragma unroll
            for (int nf = 0; nf < 4; ++nf)
              acc[mf][nf] = __builtin_amdgcn_mfma_f32_16x16x32_bf16(af[mf], bfr[nf], acc[mf][nf], 0, 0, 0);
        }
      }
      __syncthreads();
      if (!last){
        #pragma unroll
        for (int c = 0; c < 3; ++c) *(u32x4*)(Adst + c * 16) = aR[c];
        if (khb){
          #pragma unroll
          for (int it = 0; it < 17; ++it){
            int i = t + it * 512;
            if (i < BITEMS){
              int row = i / 2096, j = i % 2096, col = j >> 4, ch = j & 15;
              *(u32x4*)(lds + BOFF + row * BPITCH + col * 256 + (ch ^ ((col >> 1) & 7)) * 16) = bR[it];
            }
          }
        }
      }
      __syncthreads();
    }
  }
  unsigned short* S = (unsigned short*)lds;
  #pragma unroll
  for (int mf = 0; mf < 4; ++mf)
    #pragma unroll
    for (int nf = 0; nf < 4; ++nf){
      int wol = nw * 16 + wl;
      int pxl = nf * 64 + wol;
      int sw8 = (pxl & 7) << 3;
      #pragma unroll
      for (int j = 0; j < 4; ++j){
        int ocl = mw * 64 + mf * 16 + cg * 4 + j;
        int oc = M0 + ocl;
        float v = acc[mf][nf][j] + (oc < 384 ? rpb[oc] : cpb[oc - 384]);
        S[pxl * 128 + (ocl ^ sw8)] = f2bf(v);
      }
    }
  __syncthreads();
  #pragma unroll
  for (int it = 0; it < 8; ++it){
    int i = t + it * 512;               // 0..4095 = 256 px * 16 chunks
    int pxl = i >> 4, ch = i & 15;
    int chs = ch ^ (pxl & 7);
    int ho = ho0 + (pxl >> 6), wo = wo0 + (pxl & 63);
    u32x4 v = *(const u32x4*)&S[pxl * 128 + chs * 8];
    *(u32x4*)&cl[(((size_t)b * 128 + ho) * 128 + wo) * 768 + M0 + ch * 8] = v;
  }
}

// ---------------------------------------------------------------------------
// positional grouped conv 3x3, v2: pixel-major si [340 pix][52 ch] -> one
// aligned ushort4 per (dh,dw) serves all 4 channels of a group (36->9 reads).
// ---------------------------------------------------------------------------
__global__ __launch_bounds__(256) void k_pe(const unsigned short* __restrict__ cl,
    const float* __restrict__ rpew, const float* __restrict__ cpew,
    const float* __restrict__ rpeb, const float* __restrict__ cpeb,
    unsigned short* __restrict__ sum){
  __shared__ unsigned short si[340 * 52];  // [pix = r2*34+cc][ch pitch 52]
  __shared__ float sw[48 * 36];
  __shared__ float sb[48];
  int bid = blockIdx.x;                    // 8*16*16*4
  int wq = bid & 3, hq = (bid >> 2) & 15, slab = (bid >> 6) & 15, b = bid >> 10;
  int ch0 = slab * 48, hp0 = hq * 8, wp0 = wq * 32;
  int t = threadIdx.x;
  for (int i = t; i < 48 * 36; i += 256){
    int ocl = i / 36, r = i % 36;
    int oc = ch0 + ocl;
    const float* W = oc < 384 ? rpew : cpew;
    int o = oc < 384 ? oc : oc - 384;
    sw[i] = W[(size_t)o * 36 + r];
  }
  if (t < 48){
    int oc = ch0 + t;
    sb[t] = oc < 384 ? rpeb[oc] : cpeb[oc - 384];
  }
  for (int i = t; i < 340 * 24; i += 256){   // u32 = 2 ch at a time
    int pix = i / 24, c2 = i % 24;
    int r2 = pix / 34, cc = pix % 34;
    int hp = hp0 - 1 + r2, wp = wp0 - 1 + cc;
    unsigned v = 0;
    if (hp >= 0 && hp < 128 && wp >= 0 && wp < 128)
      v = *(const unsigned*)&cl[((size_t)b * 16384 + hp * 128 + wp) * 768 + ch0 + c2 * 2];
    *(unsigned*)&si[pix * 52 + c2 * 2] = v;
  }
  __syncthreads();
  int hpl = t >> 5, wpl = t & 31;
  unsigned int outp[24];
  #pragma unroll
  for (int g = 0; g < 12; ++g){
    float o0 = sb[g * 4], o1 = sb[g * 4 + 1], o2 = sb[g * 4 + 2], o3 = sb[g * 4 + 3];
    #pragma unroll
    for (int dh = 0; dh < 3; ++dh)
      #pragma unroll
      for (int dw = 0; dw < 3; ++dw){
        int pix = (hpl + dh) * 34 + (wpl + dw);
        u16x4 v = *(const u16x4*)&si[pix * 52 + g * 4];
        float x0 = bf2f(v[0]), x1 = bf2f(v[1]), x2 = bf2f(v[2]), x3 = bf2f(v[3]);
        int r = dh * 3 + dw;
        o0 = fmaf(sw[(g*4+0)*36 + 0*9 + r], x0, o0); o0 = fmaf(sw[(g*4+0)*36 + 1*9 + r], x1, o0);
        o0 = fmaf(sw[(g*4+0)*36 + 2*9 + r], x2, o0); o0 = fmaf(sw[(g*4+0)*36 + 3*9 + r], x3, o0);
        o1 = fmaf(sw[(g*4+1)*36 + 0*9 + r], x0, o1); o1 = fmaf(sw[(g*4+1)*36 + 1*9 + r], x1, o1);
        o1 = fmaf(sw[(g*4+1)*36 + 2*9 + r], x2, o1); o1 = fmaf(sw[(g*4+1)*36 + 3*9 + r], x3, o1);
        o2 = fmaf(sw[(g*4+2)*36 + 0*9 + r], x0, o2); o2 = fmaf(sw[(g*4+2)*36 + 1*9 + r], x1, o2);
        o2 = fmaf(sw[(g*4+2)*36 + 2*9 + r], x2, o2); o2 = fmaf(sw[(g*4+2)*36 + 3*9 + r], x3, o2);
        o3 = fmaf(sw[(g*4+3)*36 + 0*9 + r], x0, o3); o3 = fmaf(sw[(g*4+3)*36 + 1*9 + r], x1, o3);
        o3 = fmaf(sw[(g*4+3)*36 + 2*9 + r], x2, o3); o3 = fmaf(sw[(g*4+3)*36 + 3*9 + r], x3, o3);
      }
    outp[g * 2]     = (unsigned)f2bf(o0) | ((unsigned)f2bf(o1) << 16);
    outp[g * 2 + 1] = (unsigned)f2bf(o2) | ((unsigned)f2bf(o3) << 16);
  }
  size_t obase = (((size_t)b * 128 + hp0 + hpl) * 128 + wp0 + wpl) * 768 + ch0;
  #pragma unroll
  for (int c6 = 0; c6 < 6; ++c6){
    u32x4 v = { outp[c6 * 4], outp[c6 * 4 + 1], outp[c6 * 4 + 2], outp[c6 * 4 + 3] };
    *(u32x4*)&sum[obase + c6 * 8] = v;
  }
}

// ---------------------------------------------------------------------------
// FUSED hg-GEMM + minGRU scan (hg lives in LDS; no HBM intermediate).
// grid 512 = cb(8) + head(4)<<3 + b(8)<<5 + side<<8; 256 threads (4 waves).
// Block owns 16 chains x 128 steps. 32 chunks of 4 steps (N=64 px):
//   P1: GEMM M=192,K=96,N=64 from LDS B (cl tile) -> HG LDS (bf16)
//   P2: scan 4 steps (192 threads: 16 chains x 12 dgrp x 8 d) + stage next B
// LDS: A[192][208]=39936 | B[64][208]=13312 | HG[64][400]=25600 -> 78848
//   => 2 blocks/CU, grid exactly resident.
// side 0: pxl = step*128 + x ; side 1: pxl = x*128 + step  (x = cb*16+chain)
// ---------------------------------------------------------------------------
__global__ __launch_bounds__(256) void k_gruf(const unsigned short* __restrict__ cl,
    const unsigned short* __restrict__ Agr, unsigned short* __restrict__ sum){
  __shared__ char lds[78848];
  const int AOFF = 0, BOFF2 = 39936, HOFF = 53248;
  int t = threadIdx.x, lane = t & 63, wid = t >> 6;
  int wl = lane & 15, cg = lane >> 4;
  int bid = blockIdx.x;
  int cb = bid & 7, head = (bid >> 3) & 3, b = (bid >> 5) & 7, side = bid >> 8;
  size_t clbase = ((size_t)b * 16384) * 768 + side * 384 + head * 96;
  // stage A once: [192][96] -> [192][208B]
  for (int i = t; i < 2304; i += 256){
    int m = i / 12, c = i % 12;
    u32x4 v = *(const u32x4*)&Agr[((size_t)side * 192 + m) * 96 + c * 8];
    *(u32x4*)(lds + AOFF + m * 208 + c * 16) = v;
  }
  // stage B chunk 0
  for (int i = t; i < 768; i += 256){
    int px = i / 12, c = i % 12;
    int s = px >> 4, xl = px & 15;
    int xg = cb * 16 + xl;
    int pxg = side ? (xg * 128 + s) : (s * 128 + xg);
    u32x4 v = *(const u32x4*)&cl[clbase + (size_t)pxg * 768 + c * 8];
    *(u32x4*)(lds + BOFF2 + px * 208 + c * 16) = v;
  }
  int s_chain = t & 15, s_dg = t >> 4;    // scan role: active if s_dg < 12
  float h[8];
  #pragma unroll
  for (int k = 0; k < 8; ++k) h[k] = 0.f;
  __syncthreads();

  for (int ch = 0; ch < 32; ++ch){
    int s0 = ch * 4;
    // ---- P1: GEMM -> HG ----
    f32x4 acc[12];
    #pragma unroll
    for (int i = 0; i < 12; ++i) acc[i] = (f32x4){0.f, 0.f, 0.f, 0.f};
    #pragma unroll
    for (int ks = 0; ks < 3; ++ks){
      short8 bf = *(const short8*)(lds + BOFF2 + (wid * 16 + wl) * 208 + ks * 64 + cg * 16);
      #pragma unroll
      for (int mf = 0; mf < 12; ++mf){
        short8 af = *(const short8*)(lds + AOFF + (mf * 16 + wl) * 208 + ks * 64 + cg * 16);
        acc[mf] = __builtin_amdgcn_mfma_f32_16x16x32_bf16(af, bf, acc[mf], 0, 0, 0);
      }
    }
    {
      int px = wid * 16 + wl;
      #pragma unroll
      for (int mf = 0; mf < 12; ++mf){
        unsigned p0 = (unsigned)f2bf(acc[mf][0]) | ((unsigned)f2bf(acc[mf][1]) << 16);
        unsigned p1 = (unsigned)f2bf(acc[mf][2]) | ((unsigned)f2bf(acc[mf][3]) << 16);
        unsigned long long pp = (unsigned long long)p0 | ((unsigned long long)p1 << 32);
        *(unsigned long long*)(lds + HOFF + px * 400 + (mf * 16 + cg * 4) * 2) = pp;
      }
    }
    __syncthreads();
    // ---- P2: scan (4 steps) + stage next B ----
    if (s_dg < 12){
      #pragma unroll
      for (int s = 0; s < 4; ++s){
        int px = s * 16 + s_chain;
        short8 hid8 = *(const short8*)(lds + HOFF + px * 400 + s_dg * 16);
        short8 gat8 = *(const short8*)(lds + HOFF + px * 400 + 192 + s_dg * 16);
        int xg = cb * 16 + s_chain;
        int pxg = side ? (xg * 128 + (s0 + s)) : ((s0 + s) * 128 + xg);
        unsigned short* sp = (unsigned short*)&sum[clbase + (size_t)pxg * 768 + s_dg * 8];
        u32x4 sv = *(u32x4*)sp;
        unsigned short* svp = (unsigned short*)&sv;
        #pragma unroll
        for (int k = 0; k < 8; ++k){
          float hid = bf2f((unsigned short)hid8[k]);
          float gat = bf2f((unsigned short)gat8[k]);
          float z  = 1.f / (1.f + __expf(-gat));
          float th = hid >= 0.f ? hid + 0.5f : 1.f / (1.f + __expf(-hid));
          h[k] += z * (th - h[k]);
          svp[k] = f2bf(bf2f(svp[k]) + h[k]);
        }
        *(u32x4*)sp = sv;
      }
    }
    if (ch < 31){
      int sn = (ch + 1) * 4;
      for (int i = t; i < 768; i += 256){
        int px = i / 12, c = i % 12;
        int s = px >> 4, xl = px & 15;
        int xg = cb * 16 + xl;
        int pxg = side ? (xg * 128 + (sn + s)) : ((sn + s) * 128 + xg);
        u32x4 v = *(const u32x4*)&cl[clbase + (size_t)pxg * 768 + c * 8];
        *(u32x4*)(lds + BOFF2 + px * 208 + c * 16) = v;
      }
    }
    __syncthreads();
  }
}

// ---------------------------------------------------------------------------
// unpatch, v2 (validated round 11): XCD-grouped 1D grid.
// ---------------------------------------------------------------------------
__global__ __launch_bounds__(256) void k_unpatch(const unsigned short* __restrict__ sum,
    const unsigned short* __restrict__ Aun, const float* __restrict__ bun,
    float* __restrict__ out){
  __shared__ char lds[53248];            // A [128][208B] | B [128][208B]
  int t = threadIdx.x, lane = t & 63;
  int wid = t >> 6, mw = wid >> 1, nw = wid & 1;
  int bid = blockIdx.x;                  // 3072 = 8 xcd * (128 pgrp * 3 m)
  int xcd = bid & 7, rr = bid >> 3;
  int mt = rr % 3, pgrp = rr / 3;
  int M0 = mt * 128;
  size_t N0 = (size_t)(pgrp * 8 + xcd) * 128;
  f32x4 acc[4][4];
  #pragma unroll
  for (int i = 0; i < 4; ++i)
    #pragma unroll
    for (int j = 0; j < 4; ++j) acc[i][j] = (f32x4){0.f, 0.f, 0.f, 0.f};
  for (int kc = 0; kc < 8; ++kc){
    __syncthreads();
    for (int i = t; i < 1536; i += 256){
      int m = i / 12, c = i % 12;
      u32x4 v = *(const u32x4*)&Aun[(size_t)(M0 + m) * 768 + kc * 96 + c * 8];
      *(u32x4*)(lds + m * 208 + c * 16) = v;
    }
    for (int i = t; i < 1536; i += 256){
      int px = i / 12, c = i % 12;
      u32x4 v = *(const u32x4*)&sum[(N0 + px) * 768 + kc * 96 + c * 8];
      *(u32x4*)(lds + 26624 + px * 208 + c * 16) = v;
    }
    __syncthreads();
    #pragma unroll
    for (int ks = 0; ks < 3; ++ks){
      short8 af[4], bfr[4];
      #pragma unroll
      for (int mf = 0; mf < 4; ++mf)
        af[mf] = *(const short8*)(lds + (mw * 64 + mf * 16 + (lane & 15)) * 208 + ks * 64 + (lane >> 4) * 16);
      #pragma unroll
      for (int nf = 0; nf < 4; ++nf)
        bfr[nf] = *(const short8*)(lds + 26624 + (nw * 64 + nf * 16 + (lane & 15)) * 208 + ks * 64 + (lane >> 4) * 16);
      #pragma unroll
      for (int mf = 0; mf < 4; ++mf)
        #pragma unroll
        for (int nf = 0; nf < 4; ++nf)
          acc[mf][nf] = __builtin_amdgcn_mfma_f32_16x16x32_bf16(af[mf], bfr[nf], acc[mf][nf], 0, 0, 0);
    }
  }
  #pragma unroll
  for (int mf = 0; mf < 4; ++mf)
    #pragma unroll
    for (int nf = 0; nf < 4; ++nf)
      #pragma unroll
      for (int j = 0; j < 4; ++j){
        int m = M0 + mw * 64 + mf * 16 + (lane >> 4) * 4 + j;
        int co = m >> 2, p = (m >> 1) & 1, q = m & 1;
        size_t px = N0 + nw * 64 + nf * 16 + (lane & 15);
        int b = (int)(px >> 14); int pxl = (int)(px & 16383);
        int hp = pxl >> 7, wp = pxl & 127;
        out[(((size_t)b * 96 + co) * 256 + 2 * hp + p) * 256 + 2 * wp + q] = acc[mf][nf][j] + bun[co];
      }
}

// ---------------------------------------------------------------------------
extern "C" void kernel_launch(void* const* d_in, const int* in_sizes, int n_in,
                              void* d_out, int out_size, void* d_ws, size_t ws_size,
                              hipStream_t stream){
  (void)in_sizes; (void)n_in; (void)out_size;
  const float* x    = (const float*)d_in[0];
  const float* rpw  = (const float*)d_in[1];
  const float* rpb  = (const float*)d_in[2];
  const float* cpw  = (const float*)d_in[3];
  const float* cpb  = (const float*)d_in[4];
  const float* rpew = (const float*)d_in[5];
  const float* rpeb = (const float*)d_in[6];
  const float* cpew = (const float*)d_in[7];
  const float* cpeb = (const float*)d_in[8];
  const float* runw = (const float*)d_in[9];
  const float* runb = (const float*)d_in[10];
  const float* cunw = (const float*)d_in[11];
  const float* cunb = (const float*)d_in[12];
  const float* rgw  = (const float*)d_in[13];
  const float* cgw  = (const float*)d_in[14];

  char* ws = (char*)d_ws;
  const size_t SZ_XT   = (size_t)8 * 260 * 260 * 128 * 2;   // 138,444,800
  const size_t OFF_A2  = SZ_XT;
  const size_t SZ_A2   = (size_t)768 * 2400 * 2;
  const size_t OFF_AUN = OFF_A2 + SZ_A2;
  const size_t SZ_AUN  = (size_t)384 * 768 * 2;
  const size_t OFF_AGR = OFF_AUN + SZ_AUN;
  const size_t SZ_AGR  = (size_t)2 * 192 * 96 * 2;
  const size_t OFF_BUN = OFF_AGR + SZ_AGR;
  const size_t OFF_HG  = ((OFF_BUN + 384) + 255) & ~(size_t)255;
  const size_t SZ_PL   = (size_t)8 * 768 * 128 * 128 * 2;   // 201,326,592
  const size_t OFF_CL  = OFF_HG + SZ_PL;
  const size_t OFF_SUM = OFF_CL + SZ_PL;
  const size_t NEED    = OFF_SUM + SZ_PL;                   // ~747 MB
  if (ws_size < NEED){
    fprintf(stderr, "kernel_launch: ws_size %zu < needed %zu\n", ws_size, NEED);
    return;
  }
  unsigned short* xt  = (unsigned short*)(ws);
  unsigned short* A2  = (unsigned short*)(ws + OFF_A2);
  unsigned short* Aun = (unsigned short*)(ws + OFF_AUN);
  unsigned short* Agr = (unsigned short*)(ws + OFF_AGR);
  float*          bun = (float*)(ws + OFF_BUN);
  unsigned short* cl  = (unsigned short*)(ws + OFF_CL);
  unsigned short* sum = (unsigned short*)(ws + OFF_SUM);
  float* out = (float*)d_out;

  hipMemsetAsync(xt, 0, SZ_XT, stream);
  k_xt  <<<dim3(8192),    dim3(256), 0, stream>>>(x, xt);
  k_pack<<<dim3(8497),    dim3(256), 0, stream>>>(rpw, cpw, runw, cunw, runb, cunb, rgw, cgw, A2, Aun, Agr, bun);
  k_conv<<<dim3(3072),    dim3(512), 0, stream>>>(xt, A2, rpb, cpb, cl);
  k_pe  <<<dim3(8192),    dim3(256), 0, stream>>>(cl, rpew, cpew, rpeb, cpeb, sum);
  k_gruf<<<dim3(512),     dim3(256), 0, stream>>>(cl, Agr, sum);
  k_unpatch<<<dim3(3072), dim3(256), 0, stream>>>(sum, Aun, bun, out);
}